// Round 1
// baseline (30408.517 us; speedup 1.0000x reference)
//
#include <hip/hip_runtime.h>
#include <hip/hip_cooperative_groups.h>
#include <hip/hip_fp16.h>
#include <math.h>

namespace cg = cooperative_groups;

#define H      4096
#define SEQ    2048
#define HOR    64
#define NBLK   256
#define NTHR   512
#define NWAVE  (NTHR / 64)
#define RPW    2            // rows per wave; 8 waves * 2 = 16 rows per block
#define J      16           // float4 chunks per lane per row: H/(64*4)

#define SMEM_H     (H * 4)               // 16384 B: h vector (fp32)
#define SMEM_R     (NWAVE * RPW * H * 2) // 131072 B: r_Wh rows (fp16, row-pair interleaved uint4)
#define SMEM_RED   64
#define SMEM_BYTES (SMEM_H + SMEM_R + SMEM_RED)

// ---- fence-free L3-coherent point ops (sc0 sc1 = bypass L1+L2, served by
// memory-side Infinity Cache which is coherent across XCDs). ----
__device__ __forceinline__ void store_l3_f2(float2* p, float2 v) {
    asm volatile("global_store_dwordx2 %0, %1, off sc0 sc1"
                 :: "v"(p), "v"(v) : "memory");
}
__device__ __forceinline__ float4 load_l3_f4(const float4* p) {
    float4 v;
    asm volatile("global_load_dwordx4 %0, %1, off sc0 sc1"
                 : "=v"(v) : "v"(p) : "memory");
    return v;
}
__device__ __forceinline__ void vm_drain() {
    asm volatile("s_waitcnt vmcnt(0)" ::: "memory");
}

__device__ __forceinline__ float wave_reduce(float v) {
#pragma unroll
    for (int o = 32; o > 0; o >>= 1) v += __shfl_xor(v, o, 64);
    return v;
}

__device__ __forceinline__ float dot4(float4 a, float4 b) {
    float s = a.x * b.x;
    s = fmaf(a.y, b.y, s);
    s = fmaf(a.z, b.z, s);
    s = fmaf(a.w, b.w, s);
    return s;
}

union H4U { uint2 u; __half h[4]; };

__device__ __forceinline__ uint2 pack4(float4 v) {
    H4U c;
    c.h[0] = __float2half_rn(v.x); c.h[1] = __float2half_rn(v.y);
    c.h[2] = __float2half_rn(v.z); c.h[3] = __float2half_rn(v.w);
    return c.u;
}

__device__ __forceinline__ float4 unpack4(uint2 p) {
    H4U c; c.u = p;
    return make_float4(__half2float(c.h[0]), __half2float(c.h[1]),
                       __half2float(c.h[2]), __half2float(c.h[3]));
}

// Fully weight-resident persistent GRU with TAGGED h exchange.
// h is published as float2{value, tag} where tag = (float)(t+1): the data IS
// the flag, so consumer detection and data transfer share ONE L3 round trip.
// Each wave publishes its 2 rows the moment they are ready (no publish-side
// __syncthreads, no flag array). Double buffer hA/hB + monotone tags make it
// race-free; harness re-poison 0xAAAAAAAA = negative tag = stale.
// 8B aligned global stores are single-copy atomic -> value+tag never tear.
__global__ __launch_bounds__(NTHR, 2) void gru_kernel(
    const float* __restrict__ xseq,
    const float* __restrict__ uWx, const float* __restrict__ uWh, const float* __restrict__ ubv,
    const float* __restrict__ rWx, const float* __restrict__ rWh, const float* __restrict__ rbv,
    const float* __restrict__ wxv, const float* __restrict__ Whm, const float* __restrict__ bbv,
    const float* __restrict__ Vv,  const float* __restrict__ cv,
    float* __restrict__ out, float* __restrict__ ws)
{
    cg::grid_group grid = cg::this_grid();
    extern __shared__ unsigned char smem[];
    float* hF  = (float*)smem;                         // h, 4096 fp32
    uint4* rWm = (uint4*)(smem + SMEM_H);              // r_Wh fp16, row-pair interleaved
    float* red = (float*)(smem + SMEM_H + SMEM_R);     // NWAVE partials

    const int tid  = threadIdx.x;
    const int wv   = tid >> 6;
    const int lane = tid & 63;
    const int bid  = blockIdx.x;
    const int r0   = bid * (NWAVE * RPW) + wv * RPW;
    const int r1   = r0 + 1;

    float2* hA2 = (float2*)ws;          // 4096 {h, tag}
    float2* hB2 = hA2 + H;              // 4096 {h, tag}

    // ---- one-time load: pin weights on-chip ----
    const float4* w0p = (const float4*)(Whm + (size_t)r0 * H);
    const float4* w1p = (const float4*)(Whm + (size_t)r1 * H);
    const float4* u0p = (const float4*)(uWh + (size_t)r0 * H);
    const float4* u1p = (const float4*)(uWh + (size_t)r1 * H);
    const float4* p0p = (const float4*)(rWh + (size_t)r0 * H);
    const float4* p1p = (const float4*)(rWh + (size_t)r1 * H);

    float4 wA[J], wB[J];
    uint2  uA[J], uB[J];
    uint4* rsm = rWm + wv * (H / 4);    // 1024 uint4 per wave (both rows)

#pragma unroll
    for (int j = 0; j < J; ++j) {
        const int idx = j * 64 + lane;
        wA[j] = w0p[idx];
        wB[j] = w1p[idx];
        uA[j] = pack4(u0p[idx]);
        uB[j] = pack4(u1p[idx]);
        const uint2 a = pack4(p0p[idx]);
        const uint2 b = pack4(p1p[idx]);
        rsm[idx] = make_uint4(a.x, a.y, b.x, b.y);
    }
#pragma unroll
    for (int j = 0; j < J; ++j) {
        asm volatile("" : "+v"(wA[j].x), "+v"(wA[j].y), "+v"(wA[j].z), "+v"(wA[j].w));
        asm volatile("" : "+v"(wB[j].x), "+v"(wB[j].y), "+v"(wB[j].z), "+v"(wB[j].w));
        asm volatile("" : "+v"(uA[j].x), "+v"(uA[j].y));
        asm volatile("" : "+v"(uB[j].x), "+v"(uB[j].y));
    }

    const float uwx0 = uWx[r0], uwx1 = uWx[r1], ub0 = ubv[r0], ub1 = ubv[r1];
    const float rwx0 = rWx[r0], rwx1 = rWx[r1], rb0 = rbv[r0], rb1 = rbv[r1];
    const float wx0  = wxv[r0], wx1  = wxv[r1], bb0 = bbv[r0], bb1 = bbv[r1];
    const float c0 = cv[0];

    // h0 = 0, tag = 0: each block seeds its own 16 entries straight to L3.
    if (tid < NWAVE * RPW)
        store_l3_f2(&hA2[bid * (NWAVE * RPW) + tid], make_float2(0.f, 0.f));

    grid.sync();   // one-time; its release includes a vmcnt(0) drain

    const float4* v4g = (const float4*)Vv;

#pragma unroll 1
    for (int t = 0; t < SEQ + HOR; ++t) {
        const float2* hin2  = (t & 1) ? hB2 : hA2;
        float2*       hout2 = (t & 1) ? hA2 : hB2;
        const float4* src4  = (const float4*)hin2;
        const float tagf  = (float)t;        // h_t carries tag t
        const float tagf1 = (float)(t + 1);

        // ---- poll-load tagged h: detection == data transfer, one L3 RTT ----
        // thread tid owns elements [4tid,4tid+4) and [2048+4tid,2048+4tid+4)
        float4 q0, q1, q2, q3;
        for (;;) {
            q0 = load_l3_f4(src4 + 2 * tid);
            q1 = load_l3_f4(src4 + 2 * tid + 1);
            q2 = load_l3_f4(src4 + 1024 + 2 * tid);
            q3 = load_l3_f4(src4 + 1024 + 2 * tid + 1);
            vm_drain();
            const float mn = fminf(fminf(fminf(q0.y, q0.w), fminf(q1.y, q1.w)),
                                   fminf(fminf(q2.y, q2.w), fminf(q3.y, q3.w)));
            if (mn >= tagf) break;
            __builtin_amdgcn_s_sleep(1);
        }
        __syncthreads();   // all waves done reading previous hF
        ((float4*)hF)[tid]        = make_float4(q0.x, q0.z, q1.x, q1.z);
        ((float4*)hF)[tid + NTHR] = make_float4(q2.x, q2.z, q3.x, q3.z);
        __syncthreads();   // hF ready

        float x;
        if (t < SEQ) {
            x = xseq[t];
        } else {
            // y = v.h + c0, redundantly and identically in every block
            float4 a0 = ((const float4*)hF)[tid];
            float4 a1 = ((const float4*)hF)[tid + NTHR];
            float p = dot4(a0, v4g[tid]) + dot4(a1, v4g[tid + NTHR]);
            p = wave_reduce(p);
            if (lane == 0) red[wv] = p;
            __syncthreads();
            float y = c0;
#pragma unroll
            for (int w = 0; w < NWAVE; ++w) y += red[w];
            x = y;
            if (t > SEQ && bid == 0 && tid == 0) out[t - SEQ - 1] = y;
        }

        // ---- six resident row-dots against LDS h (2 LDS reads per j) ----
        float au0 = 0.f, au1 = 0.f, ar0 = 0.f, ar1 = 0.f, aw0 = 0.f, aw1 = 0.f;
#pragma unroll
        for (int j = 0; j < J; ++j) {
            const int idx = j * 64 + lane;
            const float4 hv = ((const float4*)hF)[idx];
            aw0 = fmaf(wA[j].x, hv.x, aw0); aw0 = fmaf(wA[j].y, hv.y, aw0);
            aw0 = fmaf(wA[j].z, hv.z, aw0); aw0 = fmaf(wA[j].w, hv.w, aw0);
            aw1 = fmaf(wB[j].x, hv.x, aw1); aw1 = fmaf(wB[j].y, hv.y, aw1);
            aw1 = fmaf(wB[j].z, hv.z, aw1); aw1 = fmaf(wB[j].w, hv.w, aw1);
            const float4 ua4 = unpack4(uA[j]);
            au0 = fmaf(ua4.x, hv.x, au0); au0 = fmaf(ua4.y, hv.y, au0);
            au0 = fmaf(ua4.z, hv.z, au0); au0 = fmaf(ua4.w, hv.w, au0);
            const float4 ub4 = unpack4(uB[j]);
            au1 = fmaf(ub4.x, hv.x, au1); au1 = fmaf(ub4.y, hv.y, au1);
            au1 = fmaf(ub4.z, hv.z, au1); au1 = fmaf(ub4.w, hv.w, au1);
            const uint4 m = rsm[idx];
            const float4 ra4 = unpack4(make_uint2(m.x, m.y));
            ar0 = fmaf(ra4.x, hv.x, ar0); ar0 = fmaf(ra4.y, hv.y, ar0);
            ar0 = fmaf(ra4.z, hv.z, ar0); ar0 = fmaf(ra4.w, hv.w, ar0);
            const float4 rb4 = unpack4(make_uint2(m.z, m.w));
            ar1 = fmaf(rb4.x, hv.x, ar1); ar1 = fmaf(rb4.y, hv.y, ar1);
            ar1 = fmaf(rb4.z, hv.z, ar1); ar1 = fmaf(rb4.w, hv.w, ar1);
        }
        au0 = wave_reduce(au0); au1 = wave_reduce(au1);
        ar0 = wave_reduce(ar0); ar1 = wave_reduce(ar1);
        aw0 = wave_reduce(aw0); aw1 = wave_reduce(aw1);

        // ---- epilogue split across lanes 0/1; publish immediately per wave ----
        if (lane < 2) {
            const bool s = (lane == 1);
            const float adu = s ? au1 : au0;
            const float adr = s ? ar1 : ar0;
            const float adw = s ? aw1 : aw0;
            const float uwx = s ? uwx1 : uwx0, ubb = s ? ub1 : ub0;
            const float rwx = s ? rwx1 : rwx0, rbb = s ? rb1 : rb0;
            const float wxx = s ? wx1  : wx0,  bbb = s ? bb1 : bb0;
            const int   rr  = s ? r1 : r0;
            const float ho  = hF[rr];
            const float zu  = fmaf(uwx, x, adu + ubb);
            const float zr  = fmaf(rwx, x, adr + rbb);
            const float u   = 1.f / (1.f + expf(-zu));
            const float g   = 1.f / (1.f + expf(-zr));
            const float hh  = tanhf(fmaf(wxx, x, fmaf(g, adw, bbb)));
            const float hnew = fmaf(u, hh - ho, ho);
            store_l3_f2(&hout2[rr], make_float2(hnew, tagf1));
        }
        // no publish barrier: next iteration's pre-stage __syncthreads protects hF
    }

    // preds[63] from final h (t=2111 wrote hA with tag 2112); block 0 gathers
    if (bid == 0) {
        const float tagF = (float)(SEQ + HOR);
        const float4* src4 = (const float4*)hA2;
        float4 q0, q1, q2, q3;
        for (;;) {
            q0 = load_l3_f4(src4 + 2 * tid);
            q1 = load_l3_f4(src4 + 2 * tid + 1);
            q2 = load_l3_f4(src4 + 1024 + 2 * tid);
            q3 = load_l3_f4(src4 + 1024 + 2 * tid + 1);
            vm_drain();
            const float mn = fminf(fminf(fminf(q0.y, q0.w), fminf(q1.y, q1.w)),
                                   fminf(fminf(q2.y, q2.w), fminf(q3.y, q3.w)));
            if (mn >= tagF) break;
            __builtin_amdgcn_s_sleep(1);
        }
        __syncthreads();
        ((float4*)hF)[tid]        = make_float4(q0.x, q0.z, q1.x, q1.z);
        ((float4*)hF)[tid + NTHR] = make_float4(q2.x, q2.z, q3.x, q3.z);
        __syncthreads();
        float4 a0 = ((const float4*)hF)[tid];
        float4 a1 = ((const float4*)hF)[tid + NTHR];
        float p = dot4(a0, v4g[tid]) + dot4(a1, v4g[tid + NTHR]);
        p = wave_reduce(p);
        if (lane == 0) red[wv] = p;
        __syncthreads();
        if (tid == 0) {
            float y = c0;
            for (int w = 0; w < NWAVE; ++w) y += red[w];
            out[HOR - 1] = y;
        }
    }
}

extern "C" void kernel_launch(void* const* d_in, const int* in_sizes, int n_in,
                              void* d_out, int out_size, void* d_ws, size_t ws_size,
                              hipStream_t stream) {
    const float* xseq = (const float*)d_in[0];
    const float* uWx  = (const float*)d_in[2];
    const float* uWh  = (const float*)d_in[3];
    const float* ubv  = (const float*)d_in[4];
    const float* rWx  = (const float*)d_in[5];
    const float* rWh  = (const float*)d_in[6];
    const float* rbv  = (const float*)d_in[7];
    const float* wxv  = (const float*)d_in[8];
    const float* Whm  = (const float*)d_in[9];
    const float* bbv  = (const float*)d_in[10];
    const float* Vv   = (const float*)d_in[11];
    const float* cv   = (const float*)d_in[12];
    float* out = (float*)d_out;
    float* ws  = (float*)d_ws;

    hipFuncSetAttribute((const void*)gru_kernel,
                        hipFuncAttributeMaxDynamicSharedMemorySize, SMEM_BYTES);

    void* args[] = { &xseq, &uWx, &uWh, &ubv, &rWx, &rWh, &rbv,
                     &wxv, &Whm, &bbv, &Vv, &cv, &out, &ws };
    hipLaunchCooperativeKernel((void*)gru_kernel, dim3(NBLK), dim3(NTHR),
                               args, SMEM_BYTES, stream);
}

// Round 2
// 24118.373 us; speedup vs baseline: 1.2608x; 1.2608x over previous
//
#include <hip/hip_runtime.h>
#include <hip/hip_cooperative_groups.h>
#include <hip/hip_fp16.h>
#include <math.h>

namespace cg = cooperative_groups;

#define H      4096
#define SEQ    2048
#define HOR    64
#define NBLK   256
#define NTHR   512
#define NWAVE  (NTHR / 64)
#define RPW    2            // rows per wave; 8 waves * 2 = 16 rows per block
#define J      16           // float4 chunks per lane per row: H/(64*4)

#define NGRP   8                        // arrival tree fan-in groups (bid & 7)
#define GRP_WAVES ((NBLK / NGRP) * NWAVE)  // 256 waves per group

// ctrl[] int offsets (each hot word on its own 128B line)
#define CTRL_GRP(p,g)  ((p) * 256 + (g) * 32)
#define CTRL_ROOT(p)   (512 + (p) * 32)
#define CTRL_EPOCH     576

#define SMEM_H     (H * 4)               // 16384 B: h vector (fp32)
#define SMEM_R     (NWAVE * RPW * H * 2) // 131072 B: r_Wh rows (fp16, row-pair interleaved uint4)
#define SMEM_RED   64
#define SMEM_BYTES (SMEM_H + SMEM_R + SMEM_RED)

// ---- fence-free L3-coherent point ops (sc0 sc1 = bypass L1+L2, served by
// memory-side Infinity Cache which is coherent across XCDs). ----
__device__ __forceinline__ void store_l3_f32(float* p, float v) {
    asm volatile("global_store_dword %0, %1, off sc0 sc1"
                 :: "v"(p), "v"(v) : "memory");
}
__device__ __forceinline__ void store_l3_i32(int* p, int v) {
    asm volatile("global_store_dword %0, %1, off sc0 sc1"
                 :: "v"(p), "v"(v) : "memory");
}
__device__ __forceinline__ int load_l3_i32(const int* p) {
    int v;
    asm volatile("global_load_dword %0, %1, off sc0 sc1\n\t"
                 "s_waitcnt vmcnt(0)"
                 : "=v"(v) : "v"(p) : "memory");
    return v;
}
__device__ __forceinline__ float4 load_l3_f4(const float4* p) {
    float4 v;
    asm volatile("global_load_dwordx4 %0, %1, off sc0 sc1"
                 : "=v"(v) : "v"(p) : "memory");
    return v;
}
__device__ __forceinline__ void vm_drain() {
    asm volatile("s_waitcnt vmcnt(0)" ::: "memory");
}

__device__ __forceinline__ float wave_reduce(float v) {
#pragma unroll
    for (int o = 32; o > 0; o >>= 1) v += __shfl_xor(v, o, 64);
    return v;
}

__device__ __forceinline__ float dot4(float4 a, float4 b) {
    float s = a.x * b.x;
    s = fmaf(a.y, b.y, s);
    s = fmaf(a.z, b.z, s);
    s = fmaf(a.w, b.w, s);
    return s;
}

union H4U { uint2 u; __half h[4]; };

__device__ __forceinline__ uint2 pack4(float4 v) {
    H4U c;
    c.h[0] = __float2half_rn(v.x); c.h[1] = __float2half_rn(v.y);
    c.h[2] = __float2half_rn(v.z); c.h[3] = __float2half_rn(v.w);
    return c.u;
}

__device__ __forceinline__ float4 unpack4(uint2 p) {
    H4U c; c.u = p;
    return make_float4(__half2float(c.h[0]), __half2float(c.h[1]),
                       __half2float(c.h[2]), __half2float(c.h[3]));
}

// Fully weight-resident persistent GRU.
// Sync redesign vs 26ms baseline:
//  - per-WAVE immediate publish of h rows (no publish-side __syncthreads)
//  - wave arrival via 2-level atomic tree (8 group counters -> root), the
//    root-completer publishes ONE epoch word
//  - consumers: one thread/block busy-polls the single epoch line (no sleep),
//    then __syncthreads broadcast + one bulk 16KB gather.
// Parity-indexed counters; reset only after the final atomic RETURNS (all
// arrivals complete) and next use of that parity is a full iteration away.
__global__ __launch_bounds__(NTHR, 2) void gru_kernel(
    const float* __restrict__ xseq,
    const float* __restrict__ uWx, const float* __restrict__ uWh, const float* __restrict__ ubv,
    const float* __restrict__ rWx, const float* __restrict__ rWh, const float* __restrict__ rbv,
    const float* __restrict__ wxv, const float* __restrict__ Whm, const float* __restrict__ bbv,
    const float* __restrict__ Vv,  const float* __restrict__ cv,
    float* __restrict__ out, float* __restrict__ ws)
{
    cg::grid_group grid = cg::this_grid();
    extern __shared__ unsigned char smem[];
    float* hF  = (float*)smem;                         // h, 4096 fp32
    uint4* rWm = (uint4*)(smem + SMEM_H);              // r_Wh fp16, row-pair interleaved
    float* red = (float*)(smem + SMEM_H + SMEM_R);     // NWAVE partials

    const int tid  = threadIdx.x;
    const int wv   = tid >> 6;
    const int lane = tid & 63;
    const int bid  = blockIdx.x;
    const int r0   = bid * (NWAVE * RPW) + wv * RPW;
    const int r1   = r0 + 1;

    float* hA   = ws;
    float* hB   = ws + H;
    int*   ctrl = (int*)(ws + 2 * H);

    // ---- one-time load: pin weights on-chip ----
    const float4* w0p = (const float4*)(Whm + (size_t)r0 * H);
    const float4* w1p = (const float4*)(Whm + (size_t)r1 * H);
    const float4* u0p = (const float4*)(uWh + (size_t)r0 * H);
    const float4* u1p = (const float4*)(uWh + (size_t)r1 * H);
    const float4* p0p = (const float4*)(rWh + (size_t)r0 * H);
    const float4* p1p = (const float4*)(rWh + (size_t)r1 * H);

    float4 wA[J], wB[J];
    uint2  uA[J], uB[J];
    uint4* rsm = rWm + wv * (H / 4);    // 1024 uint4 per wave (both rows)

#pragma unroll
    for (int j = 0; j < J; ++j) {
        const int idx = j * 64 + lane;
        wA[j] = w0p[idx];
        wB[j] = w1p[idx];
        uA[j] = pack4(u0p[idx]);
        uB[j] = pack4(u1p[idx]);
        const uint2 a = pack4(p0p[idx]);
        const uint2 b = pack4(p1p[idx]);
        rsm[idx] = make_uint4(a.x, a.y, b.x, b.y);
    }
#pragma unroll
    for (int j = 0; j < J; ++j) {
        asm volatile("" : "+v"(wA[j].x), "+v"(wA[j].y), "+v"(wA[j].z), "+v"(wA[j].w));
        asm volatile("" : "+v"(wB[j].x), "+v"(wB[j].y), "+v"(wB[j].z), "+v"(wB[j].w));
        asm volatile("" : "+v"(uA[j].x), "+v"(uA[j].y));
        asm volatile("" : "+v"(uB[j].x), "+v"(uB[j].y));
    }

    const float uwx0 = uWx[r0], uwx1 = uWx[r1], ub0 = ubv[r0], ub1 = ubv[r1];
    const float rwx0 = rWx[r0], rwx1 = rWx[r1], rb0 = rbv[r0], rb1 = rbv[r1];
    const float wx0  = wxv[r0], wx1  = wxv[r1], bb0 = bbv[r0], bb1 = bbv[r1];
    const float c0 = cv[0];

    // h0 = 0: each block seeds its own 16 entries straight to L3.
    if (tid < NWAVE * RPW) store_l3_f32(&hA[bid * (NWAVE * RPW) + tid], 0.f);
    // explicit ctrl init (ws is poisoned 0xAAAAAAAA between runs)
    if (bid == 0 && tid == 0) {
#pragma unroll
        for (int p = 0; p < 2; ++p) {
#pragma unroll
            for (int g = 0; g < NGRP; ++g) store_l3_i32(&ctrl[CTRL_GRP(p, g)], 0);
            store_l3_i32(&ctrl[CTRL_ROOT(p)], 0);
        }
        store_l3_i32(&ctrl[CTRL_EPOCH], 0);
    }

    grid.sync();   // one-time; its release includes a vmcnt(0) drain

    const float4* v4g = (const float4*)Vv;

#pragma unroll 1
    for (int t = 0; t < SEQ + HOR; ++t) {
        // ---- detect h_t: single thread polls the single epoch line ----
        if (t > 0) {
            if (tid == 0) {
                while (load_l3_i32(&ctrl[CTRL_EPOCH]) < t) {}
            }
            __syncthreads();
        }

        // ---- pull h_t from L3 into LDS (2 x dwordx4 per thread) ----
        const float4* hin4 = (const float4*)((t & 1) ? hB : hA);
        float* hout = (t & 1) ? hA : hB;
        float4 s0 = load_l3_f4(&hin4[tid]);
        float4 s1 = load_l3_f4(&hin4[tid + NTHR]);
        vm_drain();
        ((float4*)hF)[tid]        = s0;
        ((float4*)hF)[tid + NTHR] = s1;
        __syncthreads();

        float x;
        if (t < SEQ) {
            x = xseq[t];
        } else {
            // y = v.h + c0, redundantly and identically in every block
            float4 a0 = ((const float4*)hF)[tid];
            float4 a1 = ((const float4*)hF)[tid + NTHR];
            float p = dot4(a0, v4g[tid]) + dot4(a1, v4g[tid + NTHR]);
            p = wave_reduce(p);
            if (lane == 0) red[wv] = p;
            __syncthreads();
            float y = c0;
#pragma unroll
            for (int w = 0; w < NWAVE; ++w) y += red[w];
            x = y;
            if (t > SEQ && bid == 0 && tid == 0) out[t - SEQ - 1] = y;
        }

        // ---- six resident row-dots against LDS h ----
        float au0 = 0.f, au1 = 0.f, ar0 = 0.f, ar1 = 0.f, aw0 = 0.f, aw1 = 0.f;
#pragma unroll
        for (int j = 0; j < J; ++j) {
            const int idx = j * 64 + lane;
            const float4 hv = ((const float4*)hF)[idx];
            aw0 = fmaf(wA[j].x, hv.x, aw0); aw0 = fmaf(wA[j].y, hv.y, aw0);
            aw0 = fmaf(wA[j].z, hv.z, aw0); aw0 = fmaf(wA[j].w, hv.w, aw0);
            aw1 = fmaf(wB[j].x, hv.x, aw1); aw1 = fmaf(wB[j].y, hv.y, aw1);
            aw1 = fmaf(wB[j].z, hv.z, aw1); aw1 = fmaf(wB[j].w, hv.w, aw1);
            const float4 ua4 = unpack4(uA[j]);
            au0 = fmaf(ua4.x, hv.x, au0); au0 = fmaf(ua4.y, hv.y, au0);
            au0 = fmaf(ua4.z, hv.z, au0); au0 = fmaf(ua4.w, hv.w, au0);
            const float4 ub4 = unpack4(uB[j]);
            au1 = fmaf(ub4.x, hv.x, au1); au1 = fmaf(ub4.y, hv.y, au1);
            au1 = fmaf(ub4.z, hv.z, au1); au1 = fmaf(ub4.w, hv.w, au1);
            const uint4 m = rsm[idx];
            const float4 ra4 = unpack4(make_uint2(m.x, m.y));
            ar0 = fmaf(ra4.x, hv.x, ar0); ar0 = fmaf(ra4.y, hv.y, ar0);
            ar0 = fmaf(ra4.z, hv.z, ar0); ar0 = fmaf(ra4.w, hv.w, ar0);
            const float4 rb4 = unpack4(make_uint2(m.z, m.w));
            ar1 = fmaf(rb4.x, hv.x, ar1); ar1 = fmaf(rb4.y, hv.y, ar1);
            ar1 = fmaf(rb4.z, hv.z, ar1); ar1 = fmaf(rb4.w, hv.w, ar1);
        }
        au0 = wave_reduce(au0); au1 = wave_reduce(au1);
        ar0 = wave_reduce(ar0); ar1 = wave_reduce(ar1);
        aw0 = wave_reduce(aw0); aw1 = wave_reduce(aw1);

        // ---- epilogue on lanes 0/1; per-wave immediate publish + arrival ----
        if (lane < 2) {
            const bool s = (lane == 1);
            const float adu = s ? au1 : au0;
            const float adr = s ? ar1 : ar0;
            const float adw = s ? aw1 : aw0;
            const float uwx = s ? uwx1 : uwx0, ubb = s ? ub1 : ub0;
            const float rwx = s ? rwx1 : rwx0, rbb = s ? rb1 : rb0;
            const float wxx = s ? wx1  : wx0,  bbb = s ? bb1 : bb0;
            const int   rr  = s ? r1 : r0;
            const float ho  = hF[rr];
            const float zu  = fmaf(uwx, x, adu + ubb);
            const float zr  = fmaf(rwx, x, adr + rbb);
            const float u   = 1.f / (1.f + expf(-zu));
            const float g   = 1.f / (1.f + expf(-zr));
            const float hh  = tanhf(fmaf(wxx, x, fmaf(g, adw, bbb)));
            const float hnew = fmaf(u, hh - ho, ho);
            store_l3_f32(&hout[rr], hnew);
        }
        vm_drain();   // wave-level: this wave's h stores are at L3
        if (lane == 0) {
            const int p = t & 1;
            const int old = atomicAdd(&ctrl[CTRL_GRP(p, bid & (NGRP - 1))], 1);
            if (old == GRP_WAVES - 1) {
                const int old2 = atomicAdd(&ctrl[CTRL_ROOT(p)], 1);
                if (old2 == NGRP - 1) {
                    // every wave grid-wide has published h_{t+1}
#pragma unroll
                    for (int g = 0; g < NGRP; ++g) store_l3_i32(&ctrl[CTRL_GRP(p, g)], 0);
                    store_l3_i32(&ctrl[CTRL_ROOT(p)], 0);
                    store_l3_i32(&ctrl[CTRL_EPOCH], t + 1);
                }
            }
        }
        // no publish barrier: next iteration's detect barrier protects hF
    }

    // preds[63] from final h (t=2111 wrote hA, epoch = 2112); block 0 gathers
    if (bid == 0) {
        if (tid == 0) {
            while (load_l3_i32(&ctrl[CTRL_EPOCH]) < SEQ + HOR) {}
        }
        __syncthreads();
        float4 s0 = load_l3_f4(&((const float4*)hA)[tid]);
        float4 s1 = load_l3_f4(&((const float4*)hA)[tid + NTHR]);
        vm_drain();
        ((float4*)hF)[tid]        = s0;
        ((float4*)hF)[tid + NTHR] = s1;
        __syncthreads();
        float4 a0 = ((const float4*)hF)[tid];
        float4 a1 = ((const float4*)hF)[tid + NTHR];
        float p = dot4(a0, v4g[tid]) + dot4(a1, v4g[tid + NTHR]);
        p = wave_reduce(p);
        if (lane == 0) red[wv] = p;
        __syncthreads();
        if (tid == 0) {
            float y = c0;
            for (int w = 0; w < NWAVE; ++w) y += red[w];
            out[HOR - 1] = y;
        }
    }
}

extern "C" void kernel_launch(void* const* d_in, const int* in_sizes, int n_in,
                              void* d_out, int out_size, void* d_ws, size_t ws_size,
                              hipStream_t stream) {
    const float* xseq = (const float*)d_in[0];
    const float* uWx  = (const float*)d_in[2];
    const float* uWh  = (const float*)d_in[3];
    const float* ubv  = (const float*)d_in[4];
    const float* rWx  = (const float*)d_in[5];
    const float* rWh  = (const float*)d_in[6];
    const float* rbv  = (const float*)d_in[7];
    const float* wxv  = (const float*)d_in[8];
    const float* Whm  = (const float*)d_in[9];
    const float* bbv  = (const float*)d_in[10];
    const float* Vv   = (const float*)d_in[11];
    const float* cv   = (const float*)d_in[12];
    float* out = (float*)d_out;
    float* ws  = (float*)d_ws;

    hipFuncSetAttribute((const void*)gru_kernel,
                        hipFuncAttributeMaxDynamicSharedMemorySize, SMEM_BYTES);

    void* args[] = { &xseq, &uWx, &uWh, &ubv, &rWx, &rWh, &rbv,
                     &wxv, &Whm, &bbv, &Vv, &cv, &out, &ws };
    hipLaunchCooperativeKernel((void*)gru_kernel, dim3(NBLK), dim3(NTHR),
                               args, SMEM_BYTES, stream);
}

// Round 4
// 20607.372 us; speedup vs baseline: 1.4756x; 1.1704x over previous
//
#include <hip/hip_runtime.h>
#include <hip/hip_cooperative_groups.h>
#include <hip/hip_fp16.h>
#include <math.h>

namespace cg = cooperative_groups;

#define H      4096
#define SEQ    2048
#define HOR    64
#define NBLK   256
#define NTHR   512
#define NWAVE  (NTHR / 64)
#define RPW    2            // rows per wave; 8 waves * 2 = 16 rows per block
#define J      16           // float4 chunks per lane per row: H/(64*4)

// control ints (offsets into cws = (int*)(ws + 2*H floats))
// flags[256] packed (8 cache lines, 1 writer per word, read only by aggregator)
#define FLAGS0   0
// 128 replicated detect lines: group g (=bid>>4), wave-slot wv -> line g*8+wv
// each on its own 128B line -> <=16 uniform pollers per line
#define DET0     512
#define DET_LINE(g,wv)  (DET0 + ((g) * NWAVE + (wv)) * 32)

#define SMEM_H     (H * 4)               // 16384 B: h vector (fp32)
#define SMEM_R     (NWAVE * RPW * H * 2) // 131072 B: r_Wh rows (fp16, row-pair interleaved uint4)
#define SMEM_RED   128                   // red[8] (AR y) + pub[16] (h publish staging)
#define SMEM_BYTES (SMEM_H + SMEM_R + SMEM_RED)

typedef float f32x4_t __attribute__((ext_vector_type(4)));

// ---- fence-free L3-coherent point ops (sc0 sc1 = bypass L1+L2, served by
// memory-side Infinity Cache which is coherent across XCDs). ----
__device__ __forceinline__ void store_l3_i32(int* p, int v) {
    asm volatile("global_store_dword %0, %1, off sc0 sc1"
                 :: "v"(p), "v"(v) : "memory");
}
// NOTE: float4 (struct) as an asm INPUT fails ("indirect register inputs");
// ext_vector_type(4) maps to a contiguous VGPR quad and is accepted.
__device__ __forceinline__ void store_l3_f4(float4* p, float4 v) {
    f32x4_t w;
    w.x = v.x; w.y = v.y; w.z = v.z; w.w = v.w;
    asm volatile("global_store_dwordx4 %0, %1, off sc0 sc1"
                 :: "v"(p), "v"(w) : "memory");
}
__device__ __forceinline__ int load_l3_i32(const int* p) {
    int v;
    asm volatile("global_load_dword %0, %1, off sc0 sc1\n\t"
                 "s_waitcnt vmcnt(0)"
                 : "=v"(v) : "v"(p) : "memory");
    return v;
}
__device__ __forceinline__ int4 load_l3_i4(const int4* p) {
    int4 v;
    asm volatile("global_load_dwordx4 %0, %1, off sc0 sc1"
                 : "=v"(v) : "v"(p) : "memory");
    return v;
}
__device__ __forceinline__ float4 load_l3_f4(const float4* p) {
    float4 v;
    asm volatile("global_load_dwordx4 %0, %1, off sc0 sc1"
                 : "=v"(v) : "v"(p) : "memory");
    return v;
}
__device__ __forceinline__ void vm_drain() {
    asm volatile("s_waitcnt vmcnt(0)" ::: "memory");
}

__device__ __forceinline__ float wave_reduce(float v) {
#pragma unroll
    for (int o = 32; o > 0; o >>= 1) v += __shfl_xor(v, o, 64);
    return v;
}
__device__ __forceinline__ int wave_min_i32(int v) {
#pragma unroll
    for (int o = 32; o > 0; o >>= 1) {
        int u = __shfl_xor(v, o, 64);
        v = (u < v) ? u : v;
    }
    return v;
}

__device__ __forceinline__ float dot4(float4 a, float4 b) {
    float s = a.x * b.x;
    s = fmaf(a.y, b.y, s);
    s = fmaf(a.z, b.z, s);
    s = fmaf(a.w, b.w, s);
    return s;
}

union H4U { uint2 u; __half h[4]; };

__device__ __forceinline__ uint2 pack4(float4 v) {
    H4U c;
    c.h[0] = __float2half_rn(v.x); c.h[1] = __float2half_rn(v.y);
    c.h[2] = __float2half_rn(v.z); c.h[3] = __float2half_rn(v.w);
    return c.u;
}

__device__ __forceinline__ float4 unpack4(uint2 p) {
    H4U c; c.u = p;
    return make_float4(__half2float(c.h[0]), __half2float(c.h[1]),
                       __half2float(c.h[2]), __half2float(c.h[3]));
}

// Fully weight-resident persistent GRU.
// R4 = R3 design (compile-fixed). Theory: cost was uncached-store write
// amplification + multi-wave vmcnt drains, not detection topology.
//  - h publish: epilogue -> LDS pub[16]; after the end barrier, wave 0 lanes
//    0-3 write ONE full 64B line (4x dwordx4) per block. 256 line writes/step
//    grid-wide instead of 4096 scattered scalar stores. Only wave 0 drains.
//  - no atomics: flags[256] monotone words (1 writer each); aggregator wave
//    (block 0 wave 0) sweeps all flags with one dwordx4/lane + wave-min,
//    then writes 128 replicated detect lines (<=16 uniform pollers/line).
//  - per-wave uniform-address detect poll (1 fabric request per wave/poll),
//    each wave starts its gather immediately. 2 barriers/step.
// Poison-safety: ws re-poisoned 0xAAAAAAAA = negative int < any t+1 >= 1, so
// flags/detect need no init. Monotone all run; parity-free.
__global__ __launch_bounds__(NTHR, 2) void gru_kernel(
    const float* __restrict__ xseq,
    const float* __restrict__ uWx, const float* __restrict__ uWh, const float* __restrict__ ubv,
    const float* __restrict__ rWx, const float* __restrict__ rWh, const float* __restrict__ rbv,
    const float* __restrict__ wxv, const float* __restrict__ Whm, const float* __restrict__ bbv,
    const float* __restrict__ Vv,  const float* __restrict__ cv,
    float* __restrict__ out, float* __restrict__ ws)
{
    cg::grid_group grid = cg::this_grid();
    extern __shared__ unsigned char smem[];
    float* hF  = (float*)smem;                         // h, 4096 fp32
    uint4* rWm = (uint4*)(smem + SMEM_H);              // r_Wh fp16, row-pair interleaved
    float* red = (float*)(smem + SMEM_H + SMEM_R);     // 8 AR partials
    float* pub = red + NWAVE;                          // 16 h-publish slots

    const int tid  = threadIdx.x;
    const int wv   = tid >> 6;
    const int lane = tid & 63;
    const int bid  = blockIdx.x;
    const int r0   = bid * (NWAVE * RPW) + wv * RPW;
    const int r1   = r0 + 1;

    float* hA   = ws;
    float* hB   = ws + H;
    int*   cws  = (int*)(ws + 2 * H);
    int*   flags = cws + FLAGS0;

    // ---- one-time load: pin weights on-chip ----
    const float4* w0p = (const float4*)(Whm + (size_t)r0 * H);
    const float4* w1p = (const float4*)(Whm + (size_t)r1 * H);
    const float4* u0p = (const float4*)(uWh + (size_t)r0 * H);
    const float4* u1p = (const float4*)(uWh + (size_t)r1 * H);
    const float4* p0p = (const float4*)(rWh + (size_t)r0 * H);
    const float4* p1p = (const float4*)(rWh + (size_t)r1 * H);

    float4 wA[J], wB[J];
    uint2  uA[J], uB[J];
    uint4* rsm = rWm + wv * (H / 4);    // 1024 uint4 per wave (both rows)

#pragma unroll
    for (int j = 0; j < J; ++j) {
        const int idx = j * 64 + lane;
        wA[j] = w0p[idx];
        wB[j] = w1p[idx];
        uA[j] = pack4(u0p[idx]);
        uB[j] = pack4(u1p[idx]);
        const uint2 a = pack4(p0p[idx]);
        const uint2 b = pack4(p1p[idx]);
        rsm[idx] = make_uint4(a.x, a.y, b.x, b.y);
    }
#pragma unroll
    for (int j = 0; j < J; ++j) {
        asm volatile("" : "+v"(wA[j].x), "+v"(wA[j].y), "+v"(wA[j].z), "+v"(wA[j].w));
        asm volatile("" : "+v"(wB[j].x), "+v"(wB[j].y), "+v"(wB[j].z), "+v"(wB[j].w));
        asm volatile("" : "+v"(uA[j].x), "+v"(uA[j].y));
        asm volatile("" : "+v"(uB[j].x), "+v"(uB[j].y));
    }

    const float uwx0 = uWx[r0], uwx1 = uWx[r1], ub0 = ubv[r0], ub1 = ubv[r1];
    const float rwx0 = rWx[r0], rwx1 = rWx[r1], rb0 = rbv[r0], rb1 = rbv[r1];
    const float wx0  = wxv[r0], wx1  = wxv[r1], bb0 = bbv[r0], bb1 = bbv[r1];
    const float c0 = cv[0];

    // h0 = 0: each block seeds its own 64B line (coalesced, full-line write).
    if (tid < 4)
        store_l3_f4(&((float4*)hA)[bid * 4 + tid], make_float4(0.f, 0.f, 0.f, 0.f));

    grid.sync();   // one-time; its release includes a vmcnt(0) drain

    const float4* v4g = (const float4*)Vv;
    const int dline = DET_LINE(bid >> 4, wv);

#pragma unroll 1
    for (int t = 0; t < SEQ + HOR; ++t) {
        // ---- per-wave detect: uniform-address poll (1 request/wave/poll) ----
        if (t > 0) {
            while (load_l3_i32(&cws[dline]) < t) {}
        }

        // ---- pull h_t from L3 into LDS (2 x dwordx4 per thread) ----
        const float4* hin4 = (const float4*)((t & 1) ? hB : hA);
        float4* hout4 = (float4*)((t & 1) ? hA : hB);
        float4 s0 = load_l3_f4(&hin4[tid]);
        float4 s1 = load_l3_f4(&hin4[tid + NTHR]);
        vm_drain();
        ((float4*)hF)[tid]        = s0;
        ((float4*)hF)[tid + NTHR] = s1;
        __syncthreads();   // hF ready (also: all waves past previous publish)

        float x;
        if (t < SEQ) {
            x = xseq[t];
        } else {
            // y = v.h + c0, redundantly and identically in every block
            float4 a0 = ((const float4*)hF)[tid];
            float4 a1 = ((const float4*)hF)[tid + NTHR];
            float p = dot4(a0, v4g[tid]) + dot4(a1, v4g[tid + NTHR]);
            p = wave_reduce(p);
            if (lane == 0) red[wv] = p;
            __syncthreads();
            float y = c0;
#pragma unroll
            for (int w = 0; w < NWAVE; ++w) y += red[w];
            x = y;
            if (t > SEQ && bid == 0 && tid == 0) out[t - SEQ - 1] = y;
        }

        // ---- six resident row-dots against LDS h ----
        float au0 = 0.f, au1 = 0.f, ar0 = 0.f, ar1 = 0.f, aw0 = 0.f, aw1 = 0.f;
#pragma unroll
        for (int j = 0; j < J; ++j) {
            const int idx = j * 64 + lane;
            const float4 hv = ((const float4*)hF)[idx];
            aw0 = fmaf(wA[j].x, hv.x, aw0); aw0 = fmaf(wA[j].y, hv.y, aw0);
            aw0 = fmaf(wA[j].z, hv.z, aw0); aw0 = fmaf(wA[j].w, hv.w, aw0);
            aw1 = fmaf(wB[j].x, hv.x, aw1); aw1 = fmaf(wB[j].y, hv.y, aw1);
            aw1 = fmaf(wB[j].z, hv.z, aw1); aw1 = fmaf(wB[j].w, hv.w, aw1);
            const float4 ua4 = unpack4(uA[j]);
            au0 = fmaf(ua4.x, hv.x, au0); au0 = fmaf(ua4.y, hv.y, au0);
            au0 = fmaf(ua4.z, hv.z, au0); au0 = fmaf(ua4.w, hv.w, au0);
            const float4 ub4 = unpack4(uB[j]);
            au1 = fmaf(ub4.x, hv.x, au1); au1 = fmaf(ub4.y, hv.y, au1);
            au1 = fmaf(ub4.z, hv.z, au1); au1 = fmaf(ub4.w, hv.w, au1);
            const uint4 m = rsm[idx];
            const float4 ra4 = unpack4(make_uint2(m.x, m.y));
            ar0 = fmaf(ra4.x, hv.x, ar0); ar0 = fmaf(ra4.y, hv.y, ar0);
            ar0 = fmaf(ra4.z, hv.z, ar0); ar0 = fmaf(ra4.w, hv.w, ar0);
            const float4 rb4 = unpack4(make_uint2(m.z, m.w));
            ar1 = fmaf(rb4.x, hv.x, ar1); ar1 = fmaf(rb4.y, hv.y, ar1);
            ar1 = fmaf(rb4.z, hv.z, ar1); ar1 = fmaf(rb4.w, hv.w, ar1);
        }
        au0 = wave_reduce(au0); au1 = wave_reduce(au1);
        ar0 = wave_reduce(ar0); ar1 = wave_reduce(ar1);
        aw0 = wave_reduce(aw0); aw1 = wave_reduce(aw1);

        // ---- epilogue on lanes 0/1 -> LDS pub slots ----
        if (lane < 2) {
            const bool s = (lane == 1);
            const float adu = s ? au1 : au0;
            const float adr = s ? ar1 : ar0;
            const float adw = s ? aw1 : aw0;
            const float uwx = s ? uwx1 : uwx0, ubb = s ? ub1 : ub0;
            const float rwx = s ? rwx1 : rwx0, rbb = s ? rb1 : rb0;
            const float wxx = s ? wx1  : wx0,  bbb = s ? bb1 : bb0;
            const int   rr  = s ? r1 : r0;
            const float ho  = hF[rr];
            const float zu  = fmaf(uwx, x, adu + ubb);
            const float zr  = fmaf(rwx, x, adr + rbb);
            const float u   = 1.f / (1.f + expf(-zu));
            const float g   = 1.f / (1.f + expf(-zr));
            const float hh  = tanhf(fmaf(wxx, x, fmaf(g, adw, bbb)));
            pub[wv * RPW + (s ? 1 : 0)] = fmaf(u, hh - ho, ho);
        }
        __syncthreads();   // pub ready; also fences all hF reads this step

        // ---- wave 0 only: single full-line h publish + flag ----
        if (wv == 0) {
            if (lane < 4) {
                const float4 pv = ((const float4*)pub)[lane];
                store_l3_f4(&hout4[bid * 4 + lane], pv);
            }
            vm_drain();   // wave-uniform: the block's h line is at L3
            if (lane == 0) store_l3_i32(&flags[bid], t + 1);

            // aggregator: block 0 wave 0 sweeps all 256 flags in one
            // dwordx4/lane, then fans out to 128 replicated detect lines
            if (bid == 0) {
                const int4* fp = (const int4*)flags;
                for (;;) {
                    int4 f = load_l3_i4(fp + lane);
                    vm_drain();
                    int m = (f.x < f.y) ? f.x : f.y;
                    m = (f.z < m) ? f.z : m;
                    m = (f.w < m) ? f.w : m;
                    m = wave_min_i32(m);
                    if (m >= t + 1) break;
                }
                store_l3_i32(&cws[DET0 + lane * 32],        t + 1);
                store_l3_i32(&cws[DET0 + (lane + 64) * 32], t + 1);
            }
        }
        // no further barrier: next iteration's hF-ready barrier is collective
    }

    // preds[63] from final h (t=2111 odd wrote hA; detect already = 2112)
    if (bid == 0) {
        while (load_l3_i32(&cws[dline]) < SEQ + HOR) {}
        float4 s0 = load_l3_f4(&((const float4*)hA)[tid]);
        float4 s1 = load_l3_f4(&((const float4*)hA)[tid + NTHR]);
        vm_drain();
        ((float4*)hF)[tid]        = s0;
        ((float4*)hF)[tid + NTHR] = s1;
        __syncthreads();
        float4 a0 = ((const float4*)hF)[tid];
        float4 a1 = ((const float4*)hF)[tid + NTHR];
        float p = dot4(a0, v4g[tid]) + dot4(a1, v4g[tid + NTHR]);
        p = wave_reduce(p);
        if (lane == 0) red[wv] = p;
        __syncthreads();
        if (tid == 0) {
            float y = c0;
            for (int w = 0; w < NWAVE; ++w) y += red[w];
            out[HOR - 1] = y;
        }
    }
}

extern "C" void kernel_launch(void* const* d_in, const int* in_sizes, int n_in,
                              void* d_out, int out_size, void* d_ws, size_t ws_size,
                              hipStream_t stream) {
    const float* xseq = (const float*)d_in[0];
    const float* uWx  = (const float*)d_in[2];
    const float* uWh  = (const float*)d_in[3];
    const float* ubv  = (const float*)d_in[4];
    const float* rWx  = (const float*)d_in[5];
    const float* rWh  = (const float*)d_in[6];
    const float* rbv  = (const float*)d_in[7];
    const float* wxv  = (const float*)d_in[8];
    const float* Whm  = (const float*)d_in[9];
    const float* bbv  = (const float*)d_in[10];
    const float* Vv   = (const float*)d_in[11];
    const float* cv   = (const float*)d_in[12];
    float* out = (float*)d_out;
    float* ws  = (float*)d_ws;

    (void)hipFuncSetAttribute((const void*)gru_kernel,
                              hipFuncAttributeMaxDynamicSharedMemorySize, SMEM_BYTES);

    void* args[] = { &xseq, &uWx, &uWh, &ubv, &rWx, &rWh, &rbv,
                     &wxv, &Whm, &bbv, &Vv, &cv, &out, &ws };
    (void)hipLaunchCooperativeKernel((void*)gru_kernel, dim3(NBLK), dim3(NTHR),
                                     args, SMEM_BYTES, stream);
}